// Round 3
// baseline (89.058 us; speedup 1.0000x reference)
//
#include <hip/hip_runtime.h>
#include <stdint.h>

#define TT 384   // num directions
#define NN 384   // num points
#define RR 384   // resolution
#define D1 128
#define D2 32

// sigmoid(500y) == 1.0f (f32) for y >= 17.33/500; < 2.3e-8 for y <= -17.6/500.
#define THETA 0.0352f
#define HALF_SLOTS 191.5f          // 383/2: r(x) = (x+1)*191.5
#define BAND_ITERS 14              // ceil(2*THETA*191.5) = 14

// Module-scope accumulators: initialized once at module load, NOT re-poisoned
// by the harness's workspace fills. Placed on SEPARATE cachelines so the
// partial-sum atomics and the completion-ticket atomics don't ping-pong the
// same line across XCDs (round-2 lesson: adjacent g_acc/g_cnt + threadfences
// serialized the finalize).
__device__ __attribute__((aligned(256))) float    g_acc = 0.0f;
__device__ __attribute__((aligned(256))) unsigned g_cnt = 0u;

// ---------------- Threefry-2x32 (JAX partitionable), key = (0, 42) ----------------
__device__ inline void threefry2x32(uint32_t k0, uint32_t k1,
                                    uint32_t x0, uint32_t x1,
                                    uint32_t& o0, uint32_t& o1) {
    uint32_t ks2 = k0 ^ k1 ^ 0x1BD11BDAu;
    x0 += k0; x1 += k1;
    #define TF_ROUND(r) { x0 += x1; x1 = (x1 << (r)) | (x1 >> (32 - (r))); x1 ^= x0; }
    TF_ROUND(13) TF_ROUND(15) TF_ROUND(26) TF_ROUND(6)
    x0 += k1;  x1 += ks2 + 1u;
    TF_ROUND(17) TF_ROUND(29) TF_ROUND(16) TF_ROUND(24)
    x0 += ks2; x1 += k0 + 2u;
    TF_ROUND(13) TF_ROUND(15) TF_ROUND(26) TF_ROUND(6)
    x0 += k0;  x1 += k1 + 3u;
    TF_ROUND(17) TF_ROUND(29) TF_ROUND(16) TF_ROUND(24)
    x0 += k1;  x1 += ks2 + 4u;
    TF_ROUND(13) TF_ROUND(15) TF_ROUND(26) TF_ROUND(6)
    x0 += ks2; x1 += k0 + 5u;
    #undef TF_ROUND
    o0 = x0; o1 = x1;
}

// XLA f32 erf_inv (Giles polynomial)
__device__ inline float erfinv_f32(float x) {
    float w = -log1pf(-x * x);
    float p;
    if (w < 5.0f) {
        w = w - 2.5f;
        p =            2.81022636e-08f;
        p = fmaf(p, w, 3.43273939e-07f);
        p = fmaf(p, w, -3.5233877e-06f);
        p = fmaf(p, w, -4.39150654e-06f);
        p = fmaf(p, w, 0.00021858087f);
        p = fmaf(p, w, -0.00125372503f);
        p = fmaf(p, w, -0.00417768164f);
        p = fmaf(p, w, 0.246640727f);
        p = fmaf(p, w, 1.50140941f);
    } else {
        w = sqrtf(w) - 3.0f;
        p =            -0.000200214257f;
        p = fmaf(p, w, 0.000100950558f);
        p = fmaf(p, w, 0.00134934322f);
        p = fmaf(p, w, -0.00367342844f);
        p = fmaf(p, w, 0.00573950773f);
        p = fmaf(p, w, -0.0076224613f);
        p = fmaf(p, w, 0.00943887047f);
        p = fmaf(p, w, 1.00167406f);
        p = fmaf(p, w, 2.83297682f);
    }
    return p * x;
}

__device__ inline float bits_to_normal(uint32_t bits) {
    uint32_t fb = (bits >> 9) | 0x3F800000u;
    float f = __uint_as_float(fb) - 1.0f;               // [0, 1)
    float lo = __uint_as_float(0xBF7FFFFFu);            // nextafter(-1, 0)
    float u = f * 2.0f + lo;
    u = fmaxf(lo, u);
    return 1.41421356237f * erfinv_f32(u);
}

// Scatter one point's contribution (sign = +1 for space1, -1 for space2) into
// the difference histograms. step part: +sgn at r1 (prefix-summed later);
// band part: sgn * sigmoid at the ~14 r in the transition band.
__device__ inline void scatter_point(float p, float sgn,
                                     float* __restrict__ inc,
                                     float* __restrict__ band) {
    int r1  = (int)ceilf((p + (1.0f + THETA)) * HALF_SLOTS); // first r: lin_r >= p+theta
    int rlo = (int)ceilf((p + (1.0f - THETA)) * HALF_SLOTS); // first r: lin_r >= p-theta
    if (r1 <= 0)        atomicAdd(&inc[0], sgn);
    else if (r1 <= 383) atomicAdd(&inc[r1], sgn);
    #pragma unroll
    for (int j = 0; j < BAND_ITERS; ++j) {
        int r = rlo + j;
        if (r >= 0 && r < r1 && r < RR) {
            float lin = -1.0f + 2.0f * (float)r / 383.0f;
            float sig = __builtin_amdgcn_rcpf(1.0f + __expf(500.0f * (p - lin)));
            atomicAdd(&band[r], sgn * sig);
        }
    }
}

// Fully fused single-node kernel: one block per direction t. 384 threads.
// Phase 1: RNG + normalize both direction columns (160 normals).
// Phase 2: GEMV on row-major x, lanes-over-k coalesced float4 loads. The
//   per-row reduction is now transpose-via-LDS instead of a 5-level shfl
//   butterfly per iteration (round-2 DS-pipe analysis: 184 shuffles/thread
//   ~= 4 us of LDS-pipe serialization): each j-iter does ONE ds_write_b32 of
//   the dot4 partial into a per-wave scratch tile; afterwards each lane reads
//   back its own row's 32 partials as 8 contiguous ds_read_b128 (XOR-swizzled
//   so reads are bank-conflict-free) and sums in-registers. 184 DS ops ->
//   40 writes + 10 b128 reads per thread. Per-wave tiles: no barriers needed
//   (DS is in-order per wave). Lane l ends owning row w*64+l for BOTH spaces.
// Phase 3: histogram scatter + wave-shuffle prefix scan + per-block d^2 sum.
// Phase 4: one release-add + one acq_rel ticket per block (separate
//   cachelines); last block finalizes out[0] and resets the globals.
__global__ void __launch_bounds__(384) ect_fused(
        const float* __restrict__ x1, const float* __restrict__ x2,
        float* __restrict__ out) {
    int t = blockIdx.x;
    int tid = threadIdx.x;
    int lane = tid & 63;
    int w = tid >> 6;                 // wave id, 0..5
    __shared__ float v1s[D1];
    __shared__ float v2s[D2];
    __shared__ float inc[RR];
    __shared__ float band[RR];
    __shared__ float red[8];
    __shared__ float part1[6][32][64];   // per-wave x1 dot-partials, 48 KB
    __shared__ float part2[6][8][64];    // per-wave x2 dot-partials, 12 KB
    float* p1f = &part1[0][0][0];
    float* p2f = &part2[0][0][0];

    // ---- Phase 1: directions ----
    float g = 0.0f;
    if (tid < D1 + D2) {
        int i = (tid < D1) ? tid : tid - D1;
        uint32_t flat = (uint32_t)i * TT + (uint32_t)t;
        uint32_t o0, o1;
        threefry2x32(0u, 42u, 0u, flat, o0, o1);
        g = bits_to_normal(o0 ^ o1);
    }
    float sq = g * g;                 // waves 0,1 -> v1; wave 2 lanes<32 -> v2
    #pragma unroll
    for (int off = 32; off > 0; off >>= 1) sq += __shfl_xor(sq, off, 64);
    if (lane == 0) red[w] = sq;
    __syncthreads();
    float nrm1 = sqrtf(red[0] + red[1]);
    float nrm2 = sqrtf(red[2]);
    if (tid < D1)           v1s[tid] = g / nrm1;
    else if (tid < D1 + D2) v2s[tid - D1] = g / nrm2;
    inc[tid] = 0.0f;
    band[tid] = 0.0f;
    __syncthreads();

    // ---- Phase 2: coalesced row-major GEMV, transpose-reduce via LDS ----
    const float4* __restrict__ x1v = (const float4*)x1;
    const float4* __restrict__ x2v = (const float4*)x2;
    float4 vf1 = *(const float4*)&v1s[4 * (lane & 31)];   // k = 4*(lane&31)..+3
    float4 vf2 = *(const float4*)&v2s[4 * (lane & 7)];    // k = 4*(lane&7)..+3

    // x1 Phase A: row = w*64 + 2j + (lane>>5), k-chunk = lane&31.
    // One wave-wide float4 load = 2 full rows, perfectly coalesced.
    // Write partial to part1[w][j][lane], byte-swizzled ^((j&7)<<4)
    // (dword ^((j&7)<<2)) so Phase-B b128 reads are conflict-free.
    int base1 = (w * 64 + (lane >> 5)) * 32 + (lane & 31);
    int wb1 = w * 32 * 64;                    // dword base of this wave's tile
    #pragma unroll 8
    for (int j = 0; j < 32; ++j) {
        float4 xv = x1v[base1 + 64 * j];
        float s = xv.x * vf1.x;
        s = fmaf(xv.y, vf1.y, s);
        s = fmaf(xv.z, vf1.z, s);
        s = fmaf(xv.w, vf1.w, s);
        p1f[((wb1 + j * 64 + lane) ^ ((j & 7) << 2))] = s;
    }
    // x1 Phase B: lane l owns row w*64+l (j = l>>1, half = l&1): sum 32
    // partials = 8 contiguous float4 reads (swizzle-matched).
    float4 a4 = {0.0f, 0.0f, 0.0f, 0.0f};
    {
        int rb = wb1 + (lane >> 1) * 64 + (lane & 1) * 32;
        int q  = ((lane >> 1) & 7) << 2;
        #pragma unroll
        for (int i2 = 0; i2 < 8; ++i2) {
            float4 c = *(const float4*)&p1f[(rb + i2 * 4) ^ q];
            a4.x += c.x; a4.y += c.y; a4.z += c.z; a4.w += c.w;
        }
    }
    float p1 = (a4.x + a4.y) + (a4.z + a4.w);

    // x2 Phase A: row = w*64 + 8j + (lane>>3), k-chunk = lane&7.
    // One wave-wide float4 load = 8 full rows. Swizzle ^((j&3)<<3) on dwords.
    int base2 = (w * 64 + (lane >> 3)) * 8 + (lane & 7);
    int wb2 = w * 8 * 64;
    #pragma unroll
    for (int j = 0; j < 8; ++j) {
        float4 xv = x2v[base2 + 64 * j];
        float s = xv.x * vf2.x;
        s = fmaf(xv.y, vf2.y, s);
        s = fmaf(xv.z, vf2.z, s);
        s = fmaf(xv.w, vf2.w, s);
        p2f[((wb2 + j * 64 + lane) ^ ((j & 3) << 3))] = s;
    }
    // x2 Phase B: lane l owns row w*64+l (j = l>>3, group = l&7): sum 8
    // partials = 2 contiguous float4 reads.
    float4 b4 = {0.0f, 0.0f, 0.0f, 0.0f};
    {
        int rb = wb2 + (lane >> 3) * 64 + (lane & 7) * 8;
        int q  = ((lane >> 3) & 3) << 3;
        #pragma unroll
        for (int i2 = 0; i2 < 2; ++i2) {
            float4 c = *(const float4*)&p2f[(rb + i2 * 4) ^ q];
            b4.x += c.x; b4.y += c.y; b4.z += c.z; b4.w += c.w;
        }
    }
    float p2 = (b4.x + b4.y) + (b4.z + b4.w);

    // ---- Phase 3: histogram (thread tid holds point row tid of both spaces) ----
    scatter_point(p1,  1.0f, inc, band);
    scatter_point(p2, -1.0f, inc, band);
    __syncthreads();

    // inclusive prefix scan over inc[0..383]: wave shuffle scan + wave offsets
    float v = inc[tid];
    #pragma unroll
    for (int s = 1; s < 64; s <<= 1) {
        float u = __shfl_up(v, s, 64);
        if (lane >= s) v += u;
    }
    if (lane == 63) red[w] = v;       // wave totals
    __syncthreads();
    float off_acc = 0.0f;
    for (int j = 0; j < w; ++j) off_acc += red[j];
    v += off_acc;

    float d = v + band[tid];          // e1(r) - e2(r) at r = tid
    float s2 = d * d;
    #pragma unroll
    for (int off = 32; off > 0; off >>= 1) s2 += __shfl_xor(s2, off, 64);
    __syncthreads();                  // protect red[] reuse
    if (lane == 0) red[w] = s2;
    __syncthreads();

    // ---- Phase 4: grid accumulation, no init kernel, minimal tail ----
    if (tid == 0) {
        float s = red[0] + red[1] + red[2] + red[3] + red[4] + red[5];
        __hip_atomic_fetch_add(&g_acc, s, __ATOMIC_RELEASE,
                               __HIP_MEMORY_SCOPE_AGENT);
        unsigned old = __hip_atomic_fetch_add(&g_cnt, 1u, __ATOMIC_ACQ_REL,
                                              __HIP_MEMORY_SCOPE_AGENT);
        if (old == TT - 1) {          // last block of THIS launch
            float total = __hip_atomic_load(&g_acc, __ATOMIC_ACQUIRE,
                                            __HIP_MEMORY_SCOPE_AGENT);
            out[0] = total * (1.0f / ((float)RR * (float)TT));
            // reset for next launch (kernel-boundary makes these visible)
            __hip_atomic_store(&g_acc, 0.0f, __ATOMIC_RELAXED,
                               __HIP_MEMORY_SCOPE_AGENT);
            __hip_atomic_store(&g_cnt, 0u, __ATOMIC_RELAXED,
                               __HIP_MEMORY_SCOPE_AGENT);
        }
    }
}

extern "C" void kernel_launch(void* const* d_in, const int* in_sizes, int n_in,
                              void* d_out, int out_size, void* d_ws, size_t ws_size,
                              hipStream_t stream) {
    const float* space1 = (const float*)d_in[0];   // [384,128] row-major
    const float* space2 = (const float*)d_in[1];   // [384,32]  row-major
    float* out = (float*)d_out;

    // Workspace intentionally unused; single kernel node (no zero/init pass:
    // module globals + last-block ticket handle cross-launch reset).
    (void)d_ws; (void)ws_size;

    ect_fused<<<TT, 384, 0, stream>>>(space1, space2, out);
}

// Round 4
// 81.876 us; speedup vs baseline: 1.0877x; 1.0877x over previous
//
#include <hip/hip_runtime.h>
#include <stdint.h>

#define TT 384   // num directions
#define NN 384   // num points
#define RR 384   // resolution
#define D1 128
#define D2 32

// sigmoid(500y) == 1.0f (f32) for y >= 17.33/500; < 2.3e-8 for y <= -17.6/500.
#define THETA 0.0352f
#define HALF_SLOTS 191.5f          // 383/2: r(x) = (x+1)*191.5
#define BAND_ITERS 14              // ceil(2*THETA*191.5) = 14

// ---------------- Threefry-2x32 (JAX partitionable), key = (0, 42) ----------------
__device__ inline void threefry2x32(uint32_t k0, uint32_t k1,
                                    uint32_t x0, uint32_t x1,
                                    uint32_t& o0, uint32_t& o1) {
    uint32_t ks2 = k0 ^ k1 ^ 0x1BD11BDAu;
    x0 += k0; x1 += k1;
    #define TF_ROUND(r) { x0 += x1; x1 = (x1 << (r)) | (x1 >> (32 - (r))); x1 ^= x0; }
    TF_ROUND(13) TF_ROUND(15) TF_ROUND(26) TF_ROUND(6)
    x0 += k1;  x1 += ks2 + 1u;
    TF_ROUND(17) TF_ROUND(29) TF_ROUND(16) TF_ROUND(24)
    x0 += ks2; x1 += k0 + 2u;
    TF_ROUND(13) TF_ROUND(15) TF_ROUND(26) TF_ROUND(6)
    x0 += k0;  x1 += k1 + 3u;
    TF_ROUND(17) TF_ROUND(29) TF_ROUND(16) TF_ROUND(24)
    x0 += k1;  x1 += ks2 + 4u;
    TF_ROUND(13) TF_ROUND(15) TF_ROUND(26) TF_ROUND(6)
    x0 += ks2; x1 += k0 + 5u;
    #undef TF_ROUND
    o0 = x0; o1 = x1;
}

// XLA f32 erf_inv (Giles polynomial)
__device__ inline float erfinv_f32(float x) {
    float w = -log1pf(-x * x);
    float p;
    if (w < 5.0f) {
        w = w - 2.5f;
        p =            2.81022636e-08f;
        p = fmaf(p, w, 3.43273939e-07f);
        p = fmaf(p, w, -3.5233877e-06f);
        p = fmaf(p, w, -4.39150654e-06f);
        p = fmaf(p, w, 0.00021858087f);
        p = fmaf(p, w, -0.00125372503f);
        p = fmaf(p, w, -0.00417768164f);
        p = fmaf(p, w, 0.246640727f);
        p = fmaf(p, w, 1.50140941f);
    } else {
        w = sqrtf(w) - 3.0f;
        p =            -0.000200214257f;
        p = fmaf(p, w, 0.000100950558f);
        p = fmaf(p, w, 0.00134934322f);
        p = fmaf(p, w, -0.00367342844f);
        p = fmaf(p, w, 0.00573950773f);
        p = fmaf(p, w, -0.0076224613f);
        p = fmaf(p, w, 0.00943887047f);
        p = fmaf(p, w, 1.00167406f);
        p = fmaf(p, w, 2.83297682f);
    }
    return p * x;
}

__device__ inline float bits_to_normal(uint32_t bits) {
    uint32_t fb = (bits >> 9) | 0x3F800000u;
    float f = __uint_as_float(fb) - 1.0f;               // [0, 1)
    float lo = __uint_as_float(0xBF7FFFFFu);            // nextafter(-1, 0)
    float u = f * 2.0f + lo;
    u = fmaxf(lo, u);
    return 1.41421356237f * erfinv_f32(u);
}

// Zero the loss accumulator (trivial node; proven structure from round 1 —
// the single-node cross-XCD ticket variant measured slightly worse).
__global__ void zero_out_k(float* __restrict__ out) {
    if (threadIdx.x == 0) out[0] = 0.0f;
}

// Scatter one point's contribution (sign = +1 for space1, -1 for space2) into
// the difference histograms. step part: +sgn at r1 (prefix-summed later);
// band part: sgn * sigmoid at the ~14 r in the transition band.
__device__ inline void scatter_point(float p, float sgn,
                                     float* __restrict__ inc,
                                     float* __restrict__ band) {
    int r1  = (int)ceilf((p + (1.0f + THETA)) * HALF_SLOTS); // first r: lin_r >= p+theta
    int rlo = (int)ceilf((p + (1.0f - THETA)) * HALF_SLOTS); // first r: lin_r >= p-theta
    if (r1 <= 0)        atomicAdd(&inc[0], sgn);
    else if (r1 <= 383) atomicAdd(&inc[r1], sgn);
    #pragma unroll
    for (int j = 0; j < BAND_ITERS; ++j) {
        int r = rlo + j;
        if (r >= 0 && r < r1 && r < RR) {
            float lin = -1.0f + 2.0f * (float)r / 383.0f;
            float sig = __builtin_amdgcn_rcpf(1.0f + __expf(500.0f * (p - lin)));
            atomicAdd(&band[r], sgn * sig);
        }
    }
}

// Fully fused: one block per direction t. 384 threads.
// Phase 1: RNG + normalize both direction columns (160 normals).
// Phase 2: GEMV on row-major x, 4-LANES-PER-ROW decomposition (round-3
//   lesson: keep the reduction in registers, just make it narrow). Each lane
//   dots a quarter-row (8 float4 for x1, 2 for x2); the cross-lane reduce is
//   only over lanes differing in bits 0-1 -> shfl_xor 1 + shfl_xor 2, which
//   lower to quad_perm DPP on the VALU pipe: ZERO DS-pipe traffic, 16
//   shuffles/thread total (was 184, half of them permlane-wide).
//   Iteration j reduces 16 rows at once; lanes with (lane&3)==j keep the sum,
//   so lane l ends owning row w*64 + 16*(l&3) + (l>>2) of BOTH spaces (a
//   permutation; the histogram is row-order-agnostic).
// Phase 3: histogram scatter + wave-shuffle prefix scan + loss reduce.
__global__ void __launch_bounds__(384) ect_fused(
        const float* __restrict__ x1, const float* __restrict__ x2,
        float* __restrict__ out) {
    int t = blockIdx.x;
    int tid = threadIdx.x;
    int lane = tid & 63;
    int w = tid >> 6;                 // wave id, 0..5
    __shared__ float v1s[D1];
    __shared__ float v2s[D2];
    __shared__ float inc[RR];
    __shared__ float band[RR];
    __shared__ float red[8];

    // ---- Phase 1: directions ----
    float g = 0.0f;
    if (tid < D1 + D2) {
        int i = (tid < D1) ? tid : tid - D1;
        uint32_t flat = (uint32_t)i * TT + (uint32_t)t;
        uint32_t o0, o1;
        threefry2x32(0u, 42u, 0u, flat, o0, o1);
        g = bits_to_normal(o0 ^ o1);
    }
    float sq = g * g;                 // waves 0,1 -> v1; wave 2 lanes<32 -> v2
    #pragma unroll
    for (int off = 32; off > 0; off >>= 1) sq += __shfl_xor(sq, off, 64);
    if (lane == 0) red[w] = sq;
    __syncthreads();
    float nrm1 = sqrtf(red[0] + red[1]);
    float nrm2 = sqrtf(red[2]);
    if (tid < D1)           v1s[tid] = g / nrm1;
    else if (tid < D1 + D2) v2s[tid - D1] = g / nrm2;
    inc[tid] = 0.0f;
    band[tid] = 0.0f;
    __syncthreads();

    // ---- Phase 2: coalesced row-major GEMV, 4 lanes per row ----
    const float4* __restrict__ x1v = (const float4*)x1;
    const float4* __restrict__ x2v = (const float4*)x2;
    int l4 = lane & 3;                // position within row-group
    int lr = lane >> 2;               // row-group index, 0..15

    // Hoisted v fragments: lane's quarter-row chunks (float4 idx l4 + 4c).
    float4 vf1[8];
    #pragma unroll
    for (int c = 0; c < 8; ++c) vf1[c] = *(const float4*)&v1s[4 * l4 + 16 * c];
    float4 vf2[2];
    #pragma unroll
    for (int c = 0; c < 2; ++c) vf2[c] = *(const float4*)&v2s[4 * l4 + 16 * c];

    float p1 = 0.0f, p2 = 0.0f;

    // x1: iter j handles rows w*64 + 16j + lr. Lane's float4 idx within row:
    // l4 + 4c (c=0..7). Global idx = (w*64 + lr)*32 + l4 + 512j + 4c.
    int base1 = (w * 64 + lr) * 32 + l4;
    #pragma unroll
    for (int j = 0; j < 4; ++j) {
        float s = 0.0f;
        #pragma unroll
        for (int c = 0; c < 8; ++c) {
            float4 xv = x1v[base1 + 512 * j + 4 * c];
            s = fmaf(xv.x, vf1[c].x, s);
            s = fmaf(xv.y, vf1[c].y, s);
            s = fmaf(xv.z, vf1[c].z, s);
            s = fmaf(xv.w, vf1[c].w, s);
        }
        s += __shfl_xor(s, 1, 64);    // quad_perm DPP
        s += __shfl_xor(s, 2, 64);    // quad_perm DPP
        if (l4 == j) p1 = s;          // lane l keeps row w*64 + 16*(l&3) + (l>>2)
    }

    // x2: iter j handles rows w*64 + 16j + lr. Lane's float4 idx: l4 + 4c
    // (c=0..1). Global idx = (w*64 + lr)*8 + l4 + 128j + 4c.
    int base2 = (w * 64 + lr) * 8 + l4;
    #pragma unroll
    for (int j = 0; j < 4; ++j) {
        float s = 0.0f;
        #pragma unroll
        for (int c = 0; c < 2; ++c) {
            float4 xv = x2v[base2 + 128 * j + 4 * c];
            s = fmaf(xv.x, vf2[c].x, s);
            s = fmaf(xv.y, vf2[c].y, s);
            s = fmaf(xv.z, vf2[c].z, s);
            s = fmaf(xv.w, vf2[c].w, s);
        }
        s += __shfl_xor(s, 1, 64);
        s += __shfl_xor(s, 2, 64);
        if (l4 == j) p2 = s;          // same row as p1
    }

    // ---- Phase 3: histogram (row assignment is a permutation; scatter is
    // order-agnostic) ----
    scatter_point(p1,  1.0f, inc, band);
    scatter_point(p2, -1.0f, inc, band);
    __syncthreads();

    // inclusive prefix scan over inc[0..383]: wave shuffle scan + wave offsets
    float v = inc[tid];
    #pragma unroll
    for (int s = 1; s < 64; s <<= 1) {
        float u = __shfl_up(v, s, 64);
        if (lane >= s) v += u;
    }
    if (lane == 63) red[w] = v;       // wave totals
    __syncthreads();
    float off_acc = 0.0f;
    for (int j = 0; j < w; ++j) off_acc += red[j];
    v += off_acc;

    float d = v + band[tid];          // e1(r) - e2(r) at r = tid
    float s2 = d * d;
    #pragma unroll
    for (int off = 32; off > 0; off >>= 1) s2 += __shfl_xor(s2, off, 64);
    __syncthreads();                  // protect red[] reuse
    if (lane == 0) red[w] = s2;
    __syncthreads();
    if (tid == 0) {
        float s = red[0] + red[1] + red[2] + red[3] + red[4] + red[5];
        atomicAdd(out, s * (1.0f / ((float)RR * (float)TT)));
    }
}

extern "C" void kernel_launch(void* const* d_in, const int* in_sizes, int n_in,
                              void* d_out, int out_size, void* d_ws, size_t ws_size,
                              hipStream_t stream) {
    const float* space1 = (const float*)d_in[0];   // [384,128] row-major
    const float* space2 = (const float*)d_in[1];   // [384,32]  row-major
    float* out = (float*)d_out;

    // Workspace intentionally unused: no transpose pass.
    (void)d_ws; (void)ws_size;

    zero_out_k<<<1, 64, 0, stream>>>(out);
    ect_fused<<<TT, 384, 0, stream>>>(space1, space2, out);
}